// Round 11
// baseline (148.911 us; speedup 1.0000x reference)
//
#include <hip/hip_runtime.h>
#include <math.h>

// B=32, T=256, C=128, NEIGH=5, TOPK=4.  Two launches:
// proj:     pf=norm(x@Wpf^T), ns=norm(x@Wns^T) -> SPLIT bf16 (h/l pairs);
//           v=x@Wv^T -> transposed split bf16 vt[c][t]
// bigfused: per (b, x-tile-16): G-rows & S via split-bf16 MFMA straight from L2
//           -> LDS -> in-place rowmax conv + mask -> softmax -> MFMA PV -> out.
// R11: XCD swizzle (b = bid&31 -> same-batch blocks on same XCD) and
//      LDS 57.3->36.9KB (rowmax in place of Gb) -> 4 blocks/CU.

#define TT 256
#define CC 128

using bf16x8 = __attribute__((ext_vector_type(8))) short;
using f32x4  = __attribute__((ext_vector_type(4))) float;

__device__ __forceinline__ short bf_hi(float x) {
    unsigned u = __float_as_uint(x);
    return (short)((u + 0x7FFFu + ((u >> 16) & 1u)) >> 16);
}
__device__ __forceinline__ void bf_split(float x, short& h, short& l) {
    h = bf_hi(x);
    float hf = __uint_as_float(((unsigned)(unsigned short)h) << 16);
    l = bf_hi(x - hf);
}
__device__ __forceinline__ float bf2f(short h) {
    return __uint_as_float(((unsigned)(unsigned short)h) << 16);
}
__device__ __forceinline__ float max5(float a, float b, float c, float d, float e) {
    return fmaxf(fmaxf(fmaxf(a, b), fmaxf(c, d)), e);
}

// ---- proj: 32 rows/block, one matrix per blockIdx.y, split-bf16 MFMA (unchanged).
__global__ __launch_bounds__(256, 4) void proj_kernel(
    const float* __restrict__ x,
    const float* __restrict__ W0, const float* __restrict__ W1, const float* __restrict__ W2,
    short* __restrict__ pf_h, short* __restrict__ pf_l,
    short* __restrict__ ns_h, short* __restrict__ ns_l,
    short* __restrict__ vt_h, short* __restrict__ vt_l)
{
    __shared__ short Ah[32 * 40], Al[32 * 40];
    __shared__ short Bh[128 * 40], Bl[128 * 40];
    __shared__ float ssb[32][4];
    const int tid = threadIdx.x;
    const int row0 = blockIdx.x * 32;
    const int m = blockIdx.y;
    const float* __restrict__ W = (m == 0) ? W0 : (m == 1) ? W1 : W2;
    const int lane = tid & 63, wn = tid >> 6;
    const int quad = lane >> 4, lr = lane & 15;
    f32x4 z4 = {0.f, 0.f, 0.f, 0.f};
    f32x4 acc[2][2] = {{z4, z4}, {z4, z4}};

    for (int k0 = 0; k0 < CC; k0 += 32) {
        __syncthreads();
        {
            int r = tid >> 3, q = (tid & 7) * 4;
            float4 a4 = *(const float4*)&x[(row0 + r) * CC + k0 + q];
            short4 h4, l4;
            bf_split(a4.x, h4.x, l4.x); bf_split(a4.y, h4.y, l4.y);
            bf_split(a4.z, h4.z, l4.z); bf_split(a4.w, h4.w, l4.w);
            *(short4*)&Ah[r * 40 + q] = h4; *(short4*)&Al[r * 40 + q] = l4;
        }
        for (int i = 0; i < 4; i++) {
            int flat = i * 256 + tid, r = flat >> 3, q = (flat & 7) * 4;
            float4 b4 = *(const float4*)&W[r * CC + k0 + q];
            short4 h4, l4;
            bf_split(b4.x, h4.x, l4.x); bf_split(b4.y, h4.y, l4.y);
            bf_split(b4.z, h4.z, l4.z); bf_split(b4.w, h4.w, l4.w);
            *(short4*)&Bh[r * 40 + q] = h4; *(short4*)&Bl[r * 40 + q] = l4;
        }
        __syncthreads();
        bf16x8 ah[2], al[2], bh[2], bl[2];
        for (int ra = 0; ra < 2; ra++) {
            int ar = (16 * ra + lr) * 40 + quad * 8;
            ah[ra] = *(bf16x8*)&Ah[ar];
            al[ra] = *(bf16x8*)&Al[ar];
        }
        for (int tn = 0; tn < 2; tn++) {
            int br = (32 * wn + 16 * tn + lr) * 40 + quad * 8;
            bh[tn] = *(bf16x8*)&Bh[br];
            bl[tn] = *(bf16x8*)&Bl[br];
        }
        for (int ra = 0; ra < 2; ra++)
            for (int tn = 0; tn < 2; tn++) {
                acc[ra][tn] = __builtin_amdgcn_mfma_f32_16x16x32_bf16(ah[ra], bh[tn], acc[ra][tn], 0, 0, 0);
                acc[ra][tn] = __builtin_amdgcn_mfma_f32_16x16x32_bf16(ah[ra], bl[tn], acc[ra][tn], 0, 0, 0);
                acc[ra][tn] = __builtin_amdgcn_mfma_f32_16x16x32_bf16(al[ra], bh[tn], acc[ra][tn], 0, 0, 0);
            }
    }
    if (m < 2) {
        short* __restrict__ oh = (m == 0) ? pf_h : ns_h;
        short* __restrict__ ol = (m == 0) ? pf_l : ns_l;
        float ssp[2][4];
        for (int ra = 0; ra < 2; ra++)
            for (int reg = 0; reg < 4; reg++) {
                float s = acc[ra][0][reg] * acc[ra][0][reg]
                        + acc[ra][1][reg] * acc[ra][1][reg];
                for (int off = 1; off < 16; off <<= 1) s += __shfl_xor(s, off);
                ssp[ra][reg] = s;
            }
        if (lr == 0)
            for (int ra = 0; ra < 2; ra++)
                for (int reg = 0; reg < 4; reg++)
                    ssb[16 * ra + quad * 4 + reg][wn] = ssp[ra][reg];
        __syncthreads();
        for (int ra = 0; ra < 2; ra++)
            for (int reg = 0; reg < 4; reg++) {
                int ml = 16 * ra + quad * 4 + reg;
                float ss = ssb[ml][0] + ssb[ml][1] + ssb[ml][2] + ssb[ml][3];
                float inv = 1.f / fmaxf(sqrtf(ss), 1e-12f);
                int row = row0 + ml;
                for (int tn = 0; tn < 2; tn++) {
                    float v = acc[ra][tn][reg] * inv;
                    short h, l;
                    bf_split(v, h, l);
                    int idx = row * CC + 32 * wn + 16 * tn + lr;
                    oh[idx] = h; ol[idx] = l;
                }
            }
    } else {
        for (int ra = 0; ra < 2; ra++) {
            int rowbase = row0 + 16 * ra + quad * 4;
            int b = rowbase >> 8, t0 = rowbase & 255;
            for (int tn = 0; tn < 2; tn++) {
                int c = 32 * wn + 16 * tn + lr;
                short4 h4, l4;
                for (int reg = 0; reg < 4; reg++)
                    bf_split(acc[ra][tn][reg], ((short*)&h4)[reg], ((short*)&l4)[reg]);
                size_t o = ((size_t)b * CC + c) * TT + t0;
                *(short4*)&vt_h[o] = h4;
                *(short4*)&vt_l[o] = l4;
            }
        }
    }
}

// ---- bigfused: LDS 36864B -> 4 blocks/CU. Flat grid 512, XCD swizzle.
// LDS floats: Gb[0,5120) 20x256 (rowmax computed IN PLACE) ; Sb[5120,9216) 16x256
// overlays into dead Gb: ATH[0,2112) ATL[2112,4224) RD[4224,4288) RMX[4288,4352)
__global__ __launch_bounds__(256, 4) void bigfused(
    const short* __restrict__ pf_h, const short* __restrict__ pf_l,
    const short* __restrict__ ns_h, const short* __restrict__ ns_l,
    const int* __restrict__ inxs, const float* __restrict__ v_ns,
    const float* __restrict__ g_ns, const int* __restrict__ radj,
    const float* __restrict__ v_pf, const float* __restrict__ g_pf,
    const short* __restrict__ vt_h, const short* __restrict__ vt_l,
    float* __restrict__ out)
{
    __shared__ float lds[9216];
    float* Gb  = &lds[0];
    float* Sb  = &lds[5120];
    short* ATH = (short*)&lds[0];
    short* ATL = (short*)&lds[2112];
    float* RD  = &lds[4224];
    float* RMX = &lds[4288];

    const int tid = threadIdx.x, bid = blockIdx.x;
    const int b = bid & 31, xt = bid >> 5;       // XCD swizzle: same-b -> same XCD
    const int x0 = xt * 16;
    const int rbase = min(max(x0 - 2, 0), TT - 5);
    const int a0 = min(rbase, TT - 32);
    const int d = rbase - a0;                    // 0 except xt=15 (d=14)
    const size_t nb = (size_t)b * TT * CC;
    const int lane = tid & 63, w = tid >> 6;
    const int quad = lane >> 4, lr = lane & 15;

    // ---- Q fragments in registers (no LDS, no barrier). Query row = x0+lr.
    bf16x8 aqh[4], aql[4];
    {
        float n2 = v_ns[0]*v_ns[0] + v_ns[1]*v_ns[1] + v_ns[2]*v_ns[2] + v_ns[3]*v_ns[3];
        float sc = g_ns[0] / sqrtf(n2);
        float wq[4] = {sc*v_ns[0], sc*v_ns[1], sc*v_ns[2], sc*v_ns[3]};
        int4 id = *(const int4*)&inxs[(b * TT + x0 + lr) * 4];
        int idl[4] = {id.x, id.y, id.z, id.w};
        float qv[4][8] = {};
        for (int n = 0; n < 4; n++) {
            const short* hb = &ns_h[nb + idl[n] * CC];
            const short* lb = &ns_l[nb + idl[n] * CC];
            for (int kk = 0; kk < 4; kk++) {
                int ko = kk * 32 + quad * 8;
                bf16x8 h8 = *(const bf16x8*)&hb[ko];
                bf16x8 l8 = *(const bf16x8*)&lb[ko];
                for (int e = 0; e < 8; e++)
                    qv[kk][e] = fmaf(wq[n], bf2f(h8[e]) + bf2f(l8[e]), qv[kk][e]);
            }
        }
        for (int kk = 0; kk < 4; kk++)
            for (int e = 0; e < 8; e++)
                bf_split(qv[kk][e], ((short*)&aqh[kk])[e], ((short*)&aql[kk])[e]);
    }

    // ---- MFMA accumulate: zero barriers, operands from L2.
    const int am0 = (a0 + lr) * CC, am1 = am0 + 16 * CC;
    int bcol[4];
    for (int c = 0; c < 4; c++) bcol[c] = (c * 64 + w * 16 + lr) * CC;
    f32x4 z4 = {0.f, 0.f, 0.f, 0.f};
    f32x4 accg[2][4], accs[4];
    for (int tm = 0; tm < 2; tm++) for (int c = 0; c < 4; c++) accg[tm][c] = z4;
    for (int c = 0; c < 4; c++) accs[c] = z4;

    #pragma unroll
    for (int kk = 0; kk < 4; kk++) {
        int ko = kk * 32 + quad * 8;
        bf16x8 a0h = *(const bf16x8*)&pf_h[nb + am0 + ko];
        bf16x8 a0l = *(const bf16x8*)&pf_l[nb + am0 + ko];
        bf16x8 a1h = *(const bf16x8*)&pf_h[nb + am1 + ko];
        bf16x8 a1l = *(const bf16x8*)&pf_l[nb + am1 + ko];
        #pragma unroll
        for (int c = 0; c < 4; c++) {
            bf16x8 bph = *(const bf16x8*)&pf_h[nb + bcol[c] + ko];
            bf16x8 bpl = *(const bf16x8*)&pf_l[nb + bcol[c] + ko];
            bf16x8 bnh = *(const bf16x8*)&ns_h[nb + bcol[c] + ko];
            bf16x8 bnl = *(const bf16x8*)&ns_l[nb + bcol[c] + ko];
            accg[0][c] = __builtin_amdgcn_mfma_f32_16x16x32_bf16(a0h, bph, accg[0][c], 0, 0, 0);
            accg[0][c] = __builtin_amdgcn_mfma_f32_16x16x32_bf16(a0h, bpl, accg[0][c], 0, 0, 0);
            accg[0][c] = __builtin_amdgcn_mfma_f32_16x16x32_bf16(a0l, bph, accg[0][c], 0, 0, 0);
            accg[1][c] = __builtin_amdgcn_mfma_f32_16x16x32_bf16(a1h, bph, accg[1][c], 0, 0, 0);
            accg[1][c] = __builtin_amdgcn_mfma_f32_16x16x32_bf16(a1h, bpl, accg[1][c], 0, 0, 0);
            accg[1][c] = __builtin_amdgcn_mfma_f32_16x16x32_bf16(a1l, bph, accg[1][c], 0, 0, 0);
            accs[c]    = __builtin_amdgcn_mfma_f32_16x16x32_bf16(aqh[kk], bnh, accs[c], 0, 0, 0);
            accs[c]    = __builtin_amdgcn_mfma_f32_16x16x32_bf16(aqh[kk], bnl, accs[c], 0, 0, 0);
            accs[c]    = __builtin_amdgcn_mfma_f32_16x16x32_bf16(aql[kk], bnh, accs[c], 0, 0, 0);
        }
    }
    for (int tm = 0; tm < 2; tm++)
        for (int c = 0; c < 4; c++)
            for (int reg = 0; reg < 4; reg++) {
                int gr = 16 * tm + quad * 4 + reg;
                if (gr >= d && gr < d + 20)
                    Gb[(gr - d) * 256 + c * 64 + w * 16 + lr] = accg[tm][c][reg];
            }
    for (int c = 0; c < 4; c++)
        for (int reg = 0; reg < 4; reg++)
            Sb[(quad * 4 + reg) * 256 + c * 64 + w * 16 + lr] = accs[c][reg];
    __syncthreads();

    // ---- windowed row-max IN PLACE in Gb: per round read->barrier->write.
    for (int t = 0; t < 5; t++) {
        int task = t * 256 + tid;
        int i = task >> 6, g = task & 63;
        const float* row = &Gb[min(i, 31 - d) * 256];
        float4 X = *(float4*)&row[4 * g];
        float m0_, m1_, m2_, m3_;
        if (g == 0) {
            float4 N = *(float4*)&row[4];
            float mx = fmaxf(fmaxf(X.x, X.y), fmaxf(X.z, X.w));
            m0_ = m1_ = m2_ = fmaxf(mx, N.x);
            m3_ = max5(X.y, X.z, X.w, N.x, N.y);
        } else if (g == 63) {
            float4 P = *(float4*)&row[248];
            m0_ = max5(P.z, P.w, X.x, X.y, X.z);
            float mx = fmaxf(fmaxf(X.x, X.y), fmaxf(X.z, X.w));
            m1_ = m2_ = m3_ = fmaxf(P.w, mx);
        } else {
            float4 P = *(float4*)&row[4 * g - 4];
            float4 N = *(float4*)&row[4 * g + 4];
            m0_ = max5(P.z, P.w, X.x, X.y, X.z);
            m1_ = max5(P.w, X.x, X.y, X.z, X.w);
            m2_ = max5(X.x, X.y, X.z, X.w, N.x);
            m3_ = max5(X.y, X.z, X.w, N.x, N.y);
        }
        __syncthreads();                       // all reads of this round done
        float4 o4 = {m0_, m1_, m2_, m3_};
        *(float4*)&Gb[i * 256 + 4 * g] = o4;   // RM row i now lives in Gb row i
        __syncthreads();
    }

    // ---- logits + softmax (RM == Gb rows now)
    float n2p = 0.f;
    for (int i = 0; i < 5; i++) n2p += v_pf[i] * v_pf[i];
    float scp = g_pf[0] / sqrtf(n2p);
    float wpf[5];
    for (int i = 0; i < 5; i++) wpf[i] = scp * v_pf[i];
    const int y = tid;
    const size_t sb = (size_t)b * TT * TT;
    float lv[16];
    if (xt > 0 && xt < 15) {
        float rm[20];
        #pragma unroll
        for (int r = 0; r < 20; r++) rm[r] = Gb[r * 256 + y];
        #pragma unroll
        for (int xi = 0; xi < 16; xi++) {
            float s = wpf[0] * rm[xi];
            #pragma unroll
            for (int i = 1; i < 5; i++) s = fmaf(wpf[i], rm[xi + i], s);
            lv[xi] = s;
        }
    } else {
        for (int xi = 0; xi < 16; xi++) {
            int sxr = min(max(x0 + xi - 2, 0), TT - 5) - rbase;
            float s = 0.f;
            for (int i = 0; i < 5; i++) s = fmaf(wpf[i], Gb[(sxr + i) * 256 + y], s);
            lv[xi] = s;
        }
    }
    for (int xi = 0; xi < 16; xi++) {
        lv[xi] += Sb[xi * 256 + y];
        if (radj[sb + (x0 + xi) * TT + y] == 0) lv[xi] += -1e22f;
    }
    __syncthreads();                           // Gb (RM) dead -> overlays may write
    for (int xi = 0; xi < 16; xi++) {
        float v = lv[xi];
        for (int o = 32; o; o >>= 1) v = fmaxf(v, __shfl_xor(v, o));
        if (lane == 0) RMX[xi * 4 + w] = v;
    }
    __syncthreads();
    for (int xi = 0; xi < 16; xi++) {
        float mx = fmaxf(fmaxf(RMX[xi * 4], RMX[xi * 4 + 1]),
                         fmaxf(RMX[xi * 4 + 2], RMX[xi * 4 + 3]));
        float e = __expf(lv[xi] - mx);
        short h, l;
        bf_split(e, h, l);
        ATH[xi * 264 + y] = h;
        ATL[xi * 264 + y] = l;
        for (int o = 32; o; o >>= 1) e += __shfl_xor(e, o);
        if (lane == 0) RD[xi * 4 + w] = e;
    }
    __syncthreads();

    // ---- PV: out^T[c,q] tiles. A = vt (global split), B = attn (LDS split).
    const int c0 = w * 32;
    const short* __restrict__ vhb = vt_h + (size_t)b * CC * TT;
    const short* __restrict__ vlb = vt_l + (size_t)b * CC * TT;
    const int ar0 = (c0 + lr) * TT, ar1 = ar0 + 16 * TT;
    f32x4 acc2[2] = {z4, z4};
    #pragma unroll
    for (int k0 = 0; k0 < TT; k0 += 32) {
        int ko = k0 + quad * 8;
        bf16x8 bh = *(bf16x8*)&ATH[lr * 264 + ko];
        bf16x8 bl = *(bf16x8*)&ATL[lr * 264 + ko];
        bf16x8 a0h = *(const bf16x8*)&vhb[ar0 + ko];
        bf16x8 a0l = *(const bf16x8*)&vlb[ar0 + ko];
        bf16x8 a1h = *(const bf16x8*)&vhb[ar1 + ko];
        bf16x8 a1l = *(const bf16x8*)&vlb[ar1 + ko];
        acc2[0] = __builtin_amdgcn_mfma_f32_16x16x32_bf16(a0h, bh, acc2[0], 0, 0, 0);
        acc2[0] = __builtin_amdgcn_mfma_f32_16x16x32_bf16(a0h, bl, acc2[0], 0, 0, 0);
        acc2[0] = __builtin_amdgcn_mfma_f32_16x16x32_bf16(a0l, bh, acc2[0], 0, 0, 0);
        acc2[1] = __builtin_amdgcn_mfma_f32_16x16x32_bf16(a1h, bh, acc2[1], 0, 0, 0);
        acc2[1] = __builtin_amdgcn_mfma_f32_16x16x32_bf16(a1h, bl, acc2[1], 0, 0, 0);
        acc2[1] = __builtin_amdgcn_mfma_f32_16x16x32_bf16(a1l, bh, acc2[1], 0, 0, 0);
    }
    float sm = RD[lr * 4] + RD[lr * 4 + 1] + RD[lr * 4 + 2] + RD[lr * 4 + 3];
    float rinv = 1.f / sm;
    for (int tm = 0; tm < 2; tm++) {
        float4 r;
        r.x = acc2[tm][0] * rinv; r.y = acc2[tm][1] * rinv;
        r.z = acc2[tm][2] * rinv; r.w = acc2[tm][3] * rinv;
        *(float4*)&out[(size_t)b * TT * CC + (x0 + lr) * CC + c0 + 16 * tm + quad * 4] = r;
    }
}

extern "C" void kernel_launch(void* const* d_in, const int* in_sizes, int n_in,
                              void* d_out, int out_size, void* d_ws, size_t ws_size,
                              hipStream_t stream) {
    const float* x    = (const float*)d_in[0];
    const int*   radj = (const int*)d_in[1];
    const int*   inxs = (const int*)d_in[2];
    const float* Wpf  = (const float*)d_in[3];
    const float* Wns  = (const float*)d_in[4];
    const float* Wv   = (const float*)d_in[5];
    const float* v_pf = (const float*)d_in[6];
    const float* g_pf = (const float*)d_in[7];
    const float* v_ns = (const float*)d_in[8];
    const float* g_ns = (const float*)d_in[9];
    float* out = (float*)d_out;

    char* base = (char*)d_ws;
    short* pf_h = (short*)(base);                    // 2MB each
    short* pf_l = (short*)(base + (2u << 20));
    short* ns_h = (short*)(base + (4u << 20));
    short* ns_l = (short*)(base + (6u << 20));
    short* vt_h = (short*)(base + (8u << 20));
    short* vt_l = (short*)(base + (10u << 20));

    proj_kernel<<<dim3(256, 3), 256, 0, stream>>>(x, Wpf, Wns, Wv,
                                                  pf_h, pf_l, ns_h, ns_l, vt_h, vt_l);
    bigfused<<<512, 256, 0, stream>>>(pf_h, pf_l, ns_h, ns_l,
                                      inxs, v_ns, g_ns, radj, v_pf, g_pf,
                                      vt_h, vt_l, out);
}

// Round 12
// 130.263 us; speedup vs baseline: 1.1432x; 1.1432x over previous
//
#include <hip/hip_runtime.h>
#include <math.h>

// B=32, T=256, C=128, NEIGH=5, TOPK=4.  Two launches:
// proj:     pf=norm(x@Wpf^T), ns=norm(x@Wns^T) -> SPLIT bf16 (h/l pairs);
//           v=x@Wv^T -> transposed split bf16 vt[c][t]
// bigfused: per (b, x-tile-16): G-rows & S via split-bf16 MFMA straight from L2
//           -> LDS -> in-place rowmax conv + mask -> softmax -> MFMA PV -> out.
// R12: R11's XCD swizzle + 36.9KB LDS kept; launch_bounds back to (256,2)
//      (R11's (256,4) forced VGPR 64 -> accumulator spill -> 59MB scratch writes).

#define TT 256
#define CC 128

using bf16x8 = __attribute__((ext_vector_type(8))) short;
using f32x4  = __attribute__((ext_vector_type(4))) float;

__device__ __forceinline__ short bf_hi(float x) {
    unsigned u = __float_as_uint(x);
    return (short)((u + 0x7FFFu + ((u >> 16) & 1u)) >> 16);
}
__device__ __forceinline__ void bf_split(float x, short& h, short& l) {
    h = bf_hi(x);
    float hf = __uint_as_float(((unsigned)(unsigned short)h) << 16);
    l = bf_hi(x - hf);
}
__device__ __forceinline__ float bf2f(short h) {
    return __uint_as_float(((unsigned)(unsigned short)h) << 16);
}
__device__ __forceinline__ float max5(float a, float b, float c, float d, float e) {
    return fmaxf(fmaxf(fmaxf(a, b), fmaxf(c, d)), e);
}

// ---- proj: 32 rows/block, one matrix per blockIdx.y, split-bf16 MFMA (unchanged).
__global__ __launch_bounds__(256, 4) void proj_kernel(
    const float* __restrict__ x,
    const float* __restrict__ W0, const float* __restrict__ W1, const float* __restrict__ W2,
    short* __restrict__ pf_h, short* __restrict__ pf_l,
    short* __restrict__ ns_h, short* __restrict__ ns_l,
    short* __restrict__ vt_h, short* __restrict__ vt_l)
{
    __shared__ short Ah[32 * 40], Al[32 * 40];
    __shared__ short Bh[128 * 40], Bl[128 * 40];
    __shared__ float ssb[32][4];
    const int tid = threadIdx.x;
    const int row0 = blockIdx.x * 32;
    const int m = blockIdx.y;
    const float* __restrict__ W = (m == 0) ? W0 : (m == 1) ? W1 : W2;
    const int lane = tid & 63, wn = tid >> 6;
    const int quad = lane >> 4, lr = lane & 15;
    f32x4 z4 = {0.f, 0.f, 0.f, 0.f};
    f32x4 acc[2][2] = {{z4, z4}, {z4, z4}};

    for (int k0 = 0; k0 < CC; k0 += 32) {
        __syncthreads();
        {
            int r = tid >> 3, q = (tid & 7) * 4;
            float4 a4 = *(const float4*)&x[(row0 + r) * CC + k0 + q];
            short4 h4, l4;
            bf_split(a4.x, h4.x, l4.x); bf_split(a4.y, h4.y, l4.y);
            bf_split(a4.z, h4.z, l4.z); bf_split(a4.w, h4.w, l4.w);
            *(short4*)&Ah[r * 40 + q] = h4; *(short4*)&Al[r * 40 + q] = l4;
        }
        for (int i = 0; i < 4; i++) {
            int flat = i * 256 + tid, r = flat >> 3, q = (flat & 7) * 4;
            float4 b4 = *(const float4*)&W[r * CC + k0 + q];
            short4 h4, l4;
            bf_split(b4.x, h4.x, l4.x); bf_split(b4.y, h4.y, l4.y);
            bf_split(b4.z, h4.z, l4.z); bf_split(b4.w, h4.w, l4.w);
            *(short4*)&Bh[r * 40 + q] = h4; *(short4*)&Bl[r * 40 + q] = l4;
        }
        __syncthreads();
        bf16x8 ah[2], al[2], bh[2], bl[2];
        for (int ra = 0; ra < 2; ra++) {
            int ar = (16 * ra + lr) * 40 + quad * 8;
            ah[ra] = *(bf16x8*)&Ah[ar];
            al[ra] = *(bf16x8*)&Al[ar];
        }
        for (int tn = 0; tn < 2; tn++) {
            int br = (32 * wn + 16 * tn + lr) * 40 + quad * 8;
            bh[tn] = *(bf16x8*)&Bh[br];
            bl[tn] = *(bf16x8*)&Bl[br];
        }
        for (int ra = 0; ra < 2; ra++)
            for (int tn = 0; tn < 2; tn++) {
                acc[ra][tn] = __builtin_amdgcn_mfma_f32_16x16x32_bf16(ah[ra], bh[tn], acc[ra][tn], 0, 0, 0);
                acc[ra][tn] = __builtin_amdgcn_mfma_f32_16x16x32_bf16(ah[ra], bl[tn], acc[ra][tn], 0, 0, 0);
                acc[ra][tn] = __builtin_amdgcn_mfma_f32_16x16x32_bf16(al[ra], bh[tn], acc[ra][tn], 0, 0, 0);
            }
    }
    if (m < 2) {
        short* __restrict__ oh = (m == 0) ? pf_h : ns_h;
        short* __restrict__ ol = (m == 0) ? pf_l : ns_l;
        float ssp[2][4];
        for (int ra = 0; ra < 2; ra++)
            for (int reg = 0; reg < 4; reg++) {
                float s = acc[ra][0][reg] * acc[ra][0][reg]
                        + acc[ra][1][reg] * acc[ra][1][reg];
                for (int off = 1; off < 16; off <<= 1) s += __shfl_xor(s, off);
                ssp[ra][reg] = s;
            }
        if (lr == 0)
            for (int ra = 0; ra < 2; ra++)
                for (int reg = 0; reg < 4; reg++)
                    ssb[16 * ra + quad * 4 + reg][wn] = ssp[ra][reg];
        __syncthreads();
        for (int ra = 0; ra < 2; ra++)
            for (int reg = 0; reg < 4; reg++) {
                int ml = 16 * ra + quad * 4 + reg;
                float ss = ssb[ml][0] + ssb[ml][1] + ssb[ml][2] + ssb[ml][3];
                float inv = 1.f / fmaxf(sqrtf(ss), 1e-12f);
                int row = row0 + ml;
                for (int tn = 0; tn < 2; tn++) {
                    float v = acc[ra][tn][reg] * inv;
                    short h, l;
                    bf_split(v, h, l);
                    int idx = row * CC + 32 * wn + 16 * tn + lr;
                    oh[idx] = h; ol[idx] = l;
                }
            }
    } else {
        for (int ra = 0; ra < 2; ra++) {
            int rowbase = row0 + 16 * ra + quad * 4;
            int b = rowbase >> 8, t0 = rowbase & 255;
            for (int tn = 0; tn < 2; tn++) {
                int c = 32 * wn + 16 * tn + lr;
                short4 h4, l4;
                for (int reg = 0; reg < 4; reg++)
                    bf_split(acc[ra][tn][reg], ((short*)&h4)[reg], ((short*)&l4)[reg]);
                size_t o = ((size_t)b * CC + c) * TT + t0;
                *(short4*)&vt_h[o] = h4;
                *(short4*)&vt_l[o] = l4;
            }
        }
    }
}

// ---- bigfused: LDS 36864B; VGPR budget 256 (launch_bounds 256,2 -> no spill).
// LDS floats: Gb[0,5120) 20x256 (rowmax IN PLACE) ; Sb[5120,9216) 16x256
// overlays into dead Gb: ATH[0,2112) ATL[2112,4224) RD[4224,4288) RMX[4288,4352)
__global__ __launch_bounds__(256, 2) void bigfused(
    const short* __restrict__ pf_h, const short* __restrict__ pf_l,
    const short* __restrict__ ns_h, const short* __restrict__ ns_l,
    const int* __restrict__ inxs, const float* __restrict__ v_ns,
    const float* __restrict__ g_ns, const int* __restrict__ radj,
    const float* __restrict__ v_pf, const float* __restrict__ g_pf,
    const short* __restrict__ vt_h, const short* __restrict__ vt_l,
    float* __restrict__ out)
{
    __shared__ float lds[9216];
    float* Gb  = &lds[0];
    float* Sb  = &lds[5120];
    short* ATH = (short*)&lds[0];
    short* ATL = (short*)&lds[2112];
    float* RD  = &lds[4224];
    float* RMX = &lds[4288];

    const int tid = threadIdx.x, bid = blockIdx.x;
    const int b = bid & 31, xt = bid >> 5;       // XCD swizzle: same-b -> same XCD
    const int x0 = xt * 16;
    const int rbase = min(max(x0 - 2, 0), TT - 5);
    const int a0 = min(rbase, TT - 32);
    const int d = rbase - a0;                    // 0 except xt=15 (d=14)
    const size_t nb = (size_t)b * TT * CC;
    const int lane = tid & 63, w = tid >> 6;
    const int quad = lane >> 4, lr = lane & 15;

    // ---- Q fragments in registers (no LDS, no barrier). Query row = x0+lr.
    bf16x8 aqh[4], aql[4];
    {
        float n2 = v_ns[0]*v_ns[0] + v_ns[1]*v_ns[1] + v_ns[2]*v_ns[2] + v_ns[3]*v_ns[3];
        float sc = g_ns[0] / sqrtf(n2);
        float wq[4] = {sc*v_ns[0], sc*v_ns[1], sc*v_ns[2], sc*v_ns[3]};
        int4 id = *(const int4*)&inxs[(b * TT + x0 + lr) * 4];
        int idl[4] = {id.x, id.y, id.z, id.w};
        float qv[4][8] = {};
        for (int n = 0; n < 4; n++) {
            const short* hb = &ns_h[nb + idl[n] * CC];
            const short* lb = &ns_l[nb + idl[n] * CC];
            for (int kk = 0; kk < 4; kk++) {
                int ko = kk * 32 + quad * 8;
                bf16x8 h8 = *(const bf16x8*)&hb[ko];
                bf16x8 l8 = *(const bf16x8*)&lb[ko];
                for (int e = 0; e < 8; e++)
                    qv[kk][e] = fmaf(wq[n], bf2f(h8[e]) + bf2f(l8[e]), qv[kk][e]);
            }
        }
        for (int kk = 0; kk < 4; kk++)
            for (int e = 0; e < 8; e++)
                bf_split(qv[kk][e], ((short*)&aqh[kk])[e], ((short*)&aql[kk])[e]);
    }

    // ---- MFMA accumulate: zero barriers, operands from L2.
    const int am0 = (a0 + lr) * CC, am1 = am0 + 16 * CC;
    int bcol[4];
    for (int c = 0; c < 4; c++) bcol[c] = (c * 64 + w * 16 + lr) * CC;
    f32x4 z4 = {0.f, 0.f, 0.f, 0.f};
    f32x4 accg[2][4], accs[4];
    for (int tm = 0; tm < 2; tm++) for (int c = 0; c < 4; c++) accg[tm][c] = z4;
    for (int c = 0; c < 4; c++) accs[c] = z4;

    #pragma unroll
    for (int kk = 0; kk < 4; kk++) {
        int ko = kk * 32 + quad * 8;
        bf16x8 a0h = *(const bf16x8*)&pf_h[nb + am0 + ko];
        bf16x8 a0l = *(const bf16x8*)&pf_l[nb + am0 + ko];
        bf16x8 a1h = *(const bf16x8*)&pf_h[nb + am1 + ko];
        bf16x8 a1l = *(const bf16x8*)&pf_l[nb + am1 + ko];
        #pragma unroll
        for (int c = 0; c < 4; c++) {
            bf16x8 bph = *(const bf16x8*)&pf_h[nb + bcol[c] + ko];
            bf16x8 bpl = *(const bf16x8*)&pf_l[nb + bcol[c] + ko];
            bf16x8 bnh = *(const bf16x8*)&ns_h[nb + bcol[c] + ko];
            bf16x8 bnl = *(const bf16x8*)&ns_l[nb + bcol[c] + ko];
            accg[0][c] = __builtin_amdgcn_mfma_f32_16x16x32_bf16(a0h, bph, accg[0][c], 0, 0, 0);
            accg[0][c] = __builtin_amdgcn_mfma_f32_16x16x32_bf16(a0h, bpl, accg[0][c], 0, 0, 0);
            accg[0][c] = __builtin_amdgcn_mfma_f32_16x16x32_bf16(a0l, bph, accg[0][c], 0, 0, 0);
            accg[1][c] = __builtin_amdgcn_mfma_f32_16x16x32_bf16(a1h, bph, accg[1][c], 0, 0, 0);
            accg[1][c] = __builtin_amdgcn_mfma_f32_16x16x32_bf16(a1h, bpl, accg[1][c], 0, 0, 0);
            accg[1][c] = __builtin_amdgcn_mfma_f32_16x16x32_bf16(a1l, bph, accg[1][c], 0, 0, 0);
            accs[c]    = __builtin_amdgcn_mfma_f32_16x16x32_bf16(aqh[kk], bnh, accs[c], 0, 0, 0);
            accs[c]    = __builtin_amdgcn_mfma_f32_16x16x32_bf16(aqh[kk], bnl, accs[c], 0, 0, 0);
            accs[c]    = __builtin_amdgcn_mfma_f32_16x16x32_bf16(aql[kk], bnh, accs[c], 0, 0, 0);
        }
    }
    for (int tm = 0; tm < 2; tm++)
        for (int c = 0; c < 4; c++)
            for (int reg = 0; reg < 4; reg++) {
                int gr = 16 * tm + quad * 4 + reg;
                if (gr >= d && gr < d + 20)
                    Gb[(gr - d) * 256 + c * 64 + w * 16 + lr] = accg[tm][c][reg];
            }
    for (int c = 0; c < 4; c++)
        for (int reg = 0; reg < 4; reg++)
            Sb[(quad * 4 + reg) * 256 + c * 64 + w * 16 + lr] = accs[c][reg];
    __syncthreads();

    // ---- windowed row-max IN PLACE in Gb: per round read->barrier->write.
    for (int t = 0; t < 5; t++) {
        int task = t * 256 + tid;
        int i = task >> 6, g = task & 63;
        const float* row = &Gb[min(i, 31 - d) * 256];
        float4 X = *(float4*)&row[4 * g];
        float m0_, m1_, m2_, m3_;
        if (g == 0) {
            float4 N = *(float4*)&row[4];
            float mx = fmaxf(fmaxf(X.x, X.y), fmaxf(X.z, X.w));
            m0_ = m1_ = m2_ = fmaxf(mx, N.x);
            m3_ = max5(X.y, X.z, X.w, N.x, N.y);
        } else if (g == 63) {
            float4 P = *(float4*)&row[248];
            m0_ = max5(P.z, P.w, X.x, X.y, X.z);
            float mx = fmaxf(fmaxf(X.x, X.y), fmaxf(X.z, X.w));
            m1_ = m2_ = m3_ = fmaxf(P.w, mx);
        } else {
            float4 P = *(float4*)&row[4 * g - 4];
            float4 N = *(float4*)&row[4 * g + 4];
            m0_ = max5(P.z, P.w, X.x, X.y, X.z);
            m1_ = max5(P.w, X.x, X.y, X.z, X.w);
            m2_ = max5(X.x, X.y, X.z, X.w, N.x);
            m3_ = max5(X.y, X.z, X.w, N.x, N.y);
        }
        __syncthreads();                       // all reads of this round done
        float4 o4 = {m0_, m1_, m2_, m3_};
        *(float4*)&Gb[i * 256 + 4 * g] = o4;   // RM row i now lives in Gb row i
        __syncthreads();
    }

    // ---- logits + softmax (RM == Gb rows now)
    float n2p = 0.f;
    for (int i = 0; i < 5; i++) n2p += v_pf[i] * v_pf[i];
    float scp = g_pf[0] / sqrtf(n2p);
    float wpf[5];
    for (int i = 0; i < 5; i++) wpf[i] = scp * v_pf[i];
    const int y = tid;
    const size_t sb = (size_t)b * TT * TT;
    float lv[16];
    if (xt > 0 && xt < 15) {
        float rm[20];
        #pragma unroll
        for (int r = 0; r < 20; r++) rm[r] = Gb[r * 256 + y];
        #pragma unroll
        for (int xi = 0; xi < 16; xi++) {
            float s = wpf[0] * rm[xi];
            #pragma unroll
            for (int i = 1; i < 5; i++) s = fmaf(wpf[i], rm[xi + i], s);
            lv[xi] = s;
        }
    } else {
        for (int xi = 0; xi < 16; xi++) {
            int sxr = min(max(x0 + xi - 2, 0), TT - 5) - rbase;
            float s = 0.f;
            for (int i = 0; i < 5; i++) s = fmaf(wpf[i], Gb[(sxr + i) * 256 + y], s);
            lv[xi] = s;
        }
    }
    for (int xi = 0; xi < 16; xi++) {
        lv[xi] += Sb[xi * 256 + y];
        if (radj[sb + (x0 + xi) * TT + y] == 0) lv[xi] += -1e22f;
    }
    __syncthreads();                           // Gb (RM) dead -> overlays may write
    for (int xi = 0; xi < 16; xi++) {
        float v = lv[xi];
        for (int o = 32; o; o >>= 1) v = fmaxf(v, __shfl_xor(v, o));
        if (lane == 0) RMX[xi * 4 + w] = v;
    }
    __syncthreads();
    for (int xi = 0; xi < 16; xi++) {
        float mx = fmaxf(fmaxf(RMX[xi * 4], RMX[xi * 4 + 1]),
                         fmaxf(RMX[xi * 4 + 2], RMX[xi * 4 + 3]));
        float e = __expf(lv[xi] - mx);
        short h, l;
        bf_split(e, h, l);
        ATH[xi * 264 + y] = h;
        ATL[xi * 264 + y] = l;
        for (int o = 32; o; o >>= 1) e += __shfl_xor(e, o);
        if (lane == 0) RD[xi * 4 + w] = e;
    }
    __syncthreads();

    // ---- PV: out^T[c,q] tiles. A = vt (global split), B = attn (LDS split).
    const int c0 = w * 32;
    const short* __restrict__ vhb = vt_h + (size_t)b * CC * TT;
    const short* __restrict__ vlb = vt_l + (size_t)b * CC * TT;
    const int ar0 = (c0 + lr) * TT, ar1 = ar0 + 16 * TT;
    f32x4 acc2[2] = {z4, z4};
    #pragma unroll
    for (int k0 = 0; k0 < TT; k0 += 32) {
        int ko = k0 + quad * 8;
        bf16x8 bh = *(bf16x8*)&ATH[lr * 264 + ko];
        bf16x8 bl = *(bf16x8*)&ATL[lr * 264 + ko];
        bf16x8 a0h = *(const bf16x8*)&vhb[ar0 + ko];
        bf16x8 a0l = *(const bf16x8*)&vlb[ar0 + ko];
        bf16x8 a1h = *(const bf16x8*)&vhb[ar1 + ko];
        bf16x8 a1l = *(const bf16x8*)&vlb[ar1 + ko];
        acc2[0] = __builtin_amdgcn_mfma_f32_16x16x32_bf16(a0h, bh, acc2[0], 0, 0, 0);
        acc2[0] = __builtin_amdgcn_mfma_f32_16x16x32_bf16(a0h, bl, acc2[0], 0, 0, 0);
        acc2[0] = __builtin_amdgcn_mfma_f32_16x16x32_bf16(a0l, bh, acc2[0], 0, 0, 0);
        acc2[1] = __builtin_amdgcn_mfma_f32_16x16x32_bf16(a1h, bh, acc2[1], 0, 0, 0);
        acc2[1] = __builtin_amdgcn_mfma_f32_16x16x32_bf16(a1h, bl, acc2[1], 0, 0, 0);
        acc2[1] = __builtin_amdgcn_mfma_f32_16x16x32_bf16(a1l, bh, acc2[1], 0, 0, 0);
    }
    float sm = RD[lr * 4] + RD[lr * 4 + 1] + RD[lr * 4 + 2] + RD[lr * 4 + 3];
    float rinv = 1.f / sm;
    for (int tm = 0; tm < 2; tm++) {
        float4 r;
        r.x = acc2[tm][0] * rinv; r.y = acc2[tm][1] * rinv;
        r.z = acc2[tm][2] * rinv; r.w = acc2[tm][3] * rinv;
        *(float4*)&out[(size_t)b * TT * CC + (x0 + lr) * CC + c0 + 16 * tm + quad * 4] = r;
    }
}

extern "C" void kernel_launch(void* const* d_in, const int* in_sizes, int n_in,
                              void* d_out, int out_size, void* d_ws, size_t ws_size,
                              hipStream_t stream) {
    const float* x    = (const float*)d_in[0];
    const int*   radj = (const int*)d_in[1];
    const int*   inxs = (const int*)d_in[2];
    const float* Wpf  = (const float*)d_in[3];
    const float* Wns  = (const float*)d_in[4];
    const float* Wv   = (const float*)d_in[5];
    const float* v_pf = (const float*)d_in[6];
    const float* g_pf = (const float*)d_in[7];
    const float* v_ns = (const float*)d_in[8];
    const float* g_ns = (const float*)d_in[9];
    float* out = (float*)d_out;

    char* base = (char*)d_ws;
    short* pf_h = (short*)(base);                    // 2MB each
    short* pf_l = (short*)(base + (2u << 20));
    short* ns_h = (short*)(base + (4u << 20));
    short* ns_l = (short*)(base + (6u << 20));
    short* vt_h = (short*)(base + (8u << 20));
    short* vt_l = (short*)(base + (10u << 20));

    proj_kernel<<<dim3(256, 3), 256, 0, stream>>>(x, Wpf, Wns, Wv,
                                                  pf_h, pf_l, ns_h, ns_l, vt_h, vt_l);
    bigfused<<<512, 256, 0, stream>>>(pf_h, pf_l, ns_h, ns_l,
                                      inxs, v_ns, g_ns, radj, v_pf, g_pf,
                                      vt_h, vt_l, out);
}